// Round 22
// baseline (113.330 us; speedup 1.0000x reference)
//
#include <hip/hip_runtime.h>

#define BB 8
#define SS 1024
#define DD 1024
#define HH 8
#define HD 128
#define GN_EPS 1e-3f

typedef __attribute__((ext_vector_type(8))) short bf16x8;
typedef __attribute__((ext_vector_type(4))) float f32x4;

__device__ __forceinline__ short f2bf(float f) {
    unsigned u = __float_as_uint(f);
    return (short)((u + 0x7fffu + ((u >> 16) & 1u)) >> 16);
}
__device__ __forceinline__ float bf2f(short s) {
    return __uint_as_float(((unsigned)(unsigned short)s) << 16);
}

__device__ __forceinline__ void gload16(const void* g, void* l) {
    __builtin_amdgcn_global_load_lds((const __attribute__((address_space(1))) void*)g,
                                     (__attribute__((address_space(3))) void*)l, 16, 0, 0);
}

// ---- stage one 128x64-short tile (16 KB) via global_load_lds, 8 waves ----
// LDS: linear [row][8 chunks of 8 shorts], 128 B/row. Chunk-swizzled content:
// slot q of row r holds GLOBAL chunk q ^ (r&7) (pre-swizzled global source;
// gload_lds dest stays linear). Read side applies the same XOR.
__device__ __forceinline__ void stage_tile(const short* __restrict__ G, size_t ld, int k0,
                                           short* lds, int wid, int lane) {
#pragma unroll
    for (int i = 0; i < 2; i++) {
        const int seg = wid * 2 + i;                 // 0..15 (8 rows each)
        const int row = seg * 8 + (lane >> 3);       // 0..127
        const int chunk = (lane & 7) ^ (lane >> 3);  // slot ^ (row&7)
        gload16(G + (size_t)row * ld + k0 + chunk * 8, lds + seg * 512);
    }
}

// ------------- 128x128xK MFMA core: 8 waves, BK=64, counted-vmcnt pipeline -----------
__device__ __forceinline__ void gemm_tile_g(
    const short* __restrict__ A, size_t ldA,
    const short* __restrict__ B, size_t ldB,
    int K, short* As, short* Bs, f32x4 acc[4][2])
{
    const int tid = threadIdx.x, lane = tid & 63, wid = tid >> 6;
    const int wr = (wid >> 2) * 64, wc = (wid & 3) * 32;
    const int fr = lane & 15, fc = lane >> 4;
    const int rsw = fr & 7;
#pragma unroll
    for (int i = 0; i < 4; i++)
#pragma unroll
        for (int j = 0; j < 2; j++) acc[i][j] = (f32x4){0.f, 0.f, 0.f, 0.f};

    const int nt = K >> 6;
    stage_tile(A, ldA, 0, As, wid, lane);
    stage_tile(B, ldB, 0, Bs, wid, lane);
    if (nt > 1) {
        stage_tile(A, ldA, 64, As + 8192, wid, lane);
        stage_tile(B, ldB, 64, Bs + 8192, wid, lane);
    }
    for (int t = 0; t < nt; t++) {
        if (t + 1 < nt) asm volatile("s_waitcnt vmcnt(4)" ::: "memory");
        else            asm volatile("s_waitcnt vmcnt(0)" ::: "memory");
        __builtin_amdgcn_s_barrier();
        __builtin_amdgcn_sched_barrier(0);
        const int cur = t & 1;
        const short* as = As + (cur << 13);
        const short* bs = Bs + (cur << 13);
#pragma unroll
        for (int half = 0; half < 2; half++) {
            const int slot = ((half * 4 + fc) ^ rsw) << 3;
            bf16x8 af[4], bfv[2];
#pragma unroll
            for (int i = 0; i < 4; i++) af[i] = *(const bf16x8*)&as[(wr + i * 16 + fr) * 64 + slot];
#pragma unroll
            for (int j = 0; j < 2; j++) bfv[j] = *(const bf16x8*)&bs[(wc + j * 16 + fr) * 64 + slot];
#pragma unroll
            for (int i = 0; i < 4; i++)
#pragma unroll
                for (int j = 0; j < 2; j++)
                    acc[i][j] = __builtin_amdgcn_mfma_f32_16x16x32_bf16(af[i], bfv[j], acc[i][j], 0, 0, 0);
        }
        __builtin_amdgcn_sched_barrier(0);
        asm volatile("s_waitcnt lgkmcnt(0)" ::: "memory");
        __builtin_amdgcn_s_barrier();
        if (t + 2 < nt) {
            stage_tile(A, ldA, (t + 2) << 6, As + (cur << 13), wid, lane);
            stage_tile(B, ldB, (t + 2) << 6, Bs + (cur << 13), wid, lane);
        }
    }
}

// ---------------- prep: x->bf16, W transposes, scales, zero Sp ----------------
__global__ __launch_bounds__(256) void prep(
    const float* __restrict__ x,
    const float* __restrict__ Wq, const float* __restrict__ Wk, const float* __restrict__ Wv,
    const float* __restrict__ Wg, const float* __restrict__ Wo,
    short* __restrict__ xb, short* __restrict__ WgT, short* __restrict__ WoT,
    short* __restrict__ Wt, float* __restrict__ sQ, float* __restrict__ sK,
    float* __restrict__ Sp)
{
    __shared__ float t[32][33];
    int bid = blockIdx.x;
    const int tid = threadIdx.x;
    if (bid < 4096) {                       // x -> bf16 flat
        const size_t i = ((size_t)bid * 256 + tid) * 8;
        float4 a = *(const float4*)&x[i];
        float4 b = *(const float4*)&x[i + 4];
        bf16x8 v;
        v[0] = f2bf(a.x); v[1] = f2bf(a.y); v[2] = f2bf(a.z); v[3] = f2bf(a.w);
        v[4] = f2bf(b.x); v[5] = f2bf(b.y); v[6] = f2bf(b.z); v[7] = f2bf(b.w);
        *(bf16x8*)&xb[i] = v;
        return;
    }
    bid -= 4096;
    if (bid < 2048) {                       // Wg / Wo transpose -> bf16
        const float* __restrict__ S = (bid < 1024) ? Wg : Wo;
        short* __restrict__ D = (bid < 1024) ? WgT : WoT;
        const int tb = bid & 1023;
        const int bx = (tb & 31) * 32, by = (tb >> 5) * 32;
        const int xx = tid & 31, y0 = tid >> 5;
#pragma unroll
        for (int r = 0; r < 32; r += 8) t[y0 + r][xx] = S[(size_t)(by + y0 + r) * 1024 + bx + xx];
        __syncthreads();
#pragma unroll
        for (int r = 0; r < 32; r += 8) D[(size_t)(bx + y0 + r) * 1024 + by + xx] = f2bf(t[xx][y0 + r]);
        return;
    }
    bid -= 2048;
    if (bid < 384) {                        // 24 head matrices
        const int ht = bid >> 4, tb = bid & 15;
        const int typ = ht >> 3, h = ht & 7;
        const float* __restrict__ W = (typ == 0 ? Wq : (typ == 1 ? Wk : Wv)) + (size_t)h * HD * HD;
        short* __restrict__ D = Wt + (size_t)ht * HD * HD;
        const int bx = (tb & 3) * 32, by = (tb >> 2) * 32;
        const int xx = tid & 31, y0 = tid >> 5;
#pragma unroll
        for (int r = 0; r < 32; r += 8) t[y0 + r][xx] = W[(by + y0 + r) * HD + bx + xx];
        __syncthreads();
#pragma unroll
        for (int r = 0; r < 32; r += 8) D[(bx + y0 + r) * HD + by + xx] = f2bf(t[xx][y0 + r]);
        return;
    }
    bid -= 384;
    if (bid < 32) {                         // decay scale tables
        const int h = bid >> 2;
        const int s = (bid & 3) * 256 + tid;
        const double gamma = 1.0 - exp2((double)(-5 - h));
        const double lg = log2(gamma);
        sQ[h * SS + s] = (float)exp2(lg * (double)s);
        sK[h * SS + s] = (float)exp2(-lg * (double)s);
        return;
    }
    // last block: zero Sp[2048]
    *(float4*)&Sp[tid * 8] = (float4){0.f, 0.f, 0.f, 0.f};
    *(float4*)&Sp[tid * 8 + 4] = (float4){0.f, 0.f, 0.f, 0.f};
}

// ---------------- QKV (A-reuse): 512 blocks x 512 thr, XCD-chunked ----------------
__global__ __launch_bounds__(512) void g_qkv(
    const short* __restrict__ xb, const short* __restrict__ Wt,
    const float* __restrict__ sQ, const float* __restrict__ sK,
    short* __restrict__ Qb, short* __restrict__ Ktb, short* __restrict__ Vtb)
{
    __shared__ short As[2 * 8192], Bs[2 * 8192];
    f32x4 acc[4][2];
    const int orig = blockIdx.x;
    const int w = (orig & 7) * 64 + (orig >> 3);    // 0..511
    const int mt = w >> 3, h = w & 7;
    const int m0 = mt * 128;
    const int b = m0 >> 10, s0 = m0 & (SS - 1);
    const int bh = (b << 3) + h;
    const short* __restrict__ A = xb + (size_t)m0 * DD + h * HD;
    const int tid = threadIdx.x, lane = tid & 63, wid = tid >> 6;
    const int wr = (wid >> 2) * 64, wc = (wid & 3) * 32;
    const int r0 = (lane >> 4) * 4, c = lane & 15;
    const int fr = lane & 15, fc = lane >> 4;
    const int rsw = fr & 7;

    // prologue: both A K-tiles (resident) + first B tile
    stage_tile(A, DD, 0,  As,        wid, lane);
    stage_tile(A, DD, 64, As + 8192, wid, lane);
    stage_tile(Wt + (size_t)h * HD * HD, HD, 0, Bs, wid, lane);
    __syncthreads();

#pragma unroll
    for (int i = 0; i < 4; i++)
#pragma unroll
        for (int j = 0; j < 2; j++) acc[i][j] = (f32x4){0.f, 0.f, 0.f, 0.f};

    int sb = 0;
    for (int st = 0; st < 6; st++) {                // st = typ*2 + kt
        if (st + 1 < 6) {
            const int typn = (st + 1) >> 1, ktn = (st + 1) & 1;
            stage_tile(Wt + (size_t)(typn * 8 + h) * HD * HD, HD, ktn * 64,
                       Bs + ((sb ^ 1) << 13), wid, lane);
        }
        const int kt = st & 1;
        const short* as = As + (kt << 13);
        const short* bs = Bs + (sb << 13);
#pragma unroll
        for (int half = 0; half < 2; half++) {
            const int slot = ((half * 4 + fc) ^ rsw) << 3;
            bf16x8 af[4], bfv[2];
#pragma unroll
            for (int i = 0; i < 4; i++) af[i] = *(const bf16x8*)&as[(wr + i * 16 + fr) * 64 + slot];
#pragma unroll
            for (int j = 0; j < 2; j++) bfv[j] = *(const bf16x8*)&bs[(wc + j * 16 + fr) * 64 + slot];
#pragma unroll
            for (int i = 0; i < 4; i++)
#pragma unroll
                for (int j = 0; j < 2; j++)
                    acc[i][j] = __builtin_amdgcn_mfma_f32_16x16x32_bf16(af[i], bfv[j], acc[i][j], 0, 0, 0);
        }
        __syncthreads();                             // drains B stage + protects buffers
        sb ^= 1;
        if (kt == 1) {                               // finished a type: epilogue + reset
            const int typ = st >> 1;
            if (typ == 0) {
#pragma unroll
                for (int i = 0; i < 4; i++)
#pragma unroll
                    for (int j = 0; j < 2; j++)
#pragma unroll
                        for (int r = 0; r < 4; r++) {
                            const int s = s0 + wr + i * 16 + r0 + r;
                            Qb[((size_t)bh * SS + s) * HD + wc + j * 16 + c] =
                                f2bf(acc[i][j][r] * sQ[h * SS + s]);
                        }
            } else if (typ == 1) {
                short* __restrict__ Ob = Ktb + (size_t)bh * HD * SS;
#pragma unroll
                for (int i = 0; i < 4; i++)
#pragma unroll
                    for (int j = 0; j < 2; j++) {
                        const int tb = s0 + wr + i * 16 + r0;
                        const int d = wc + j * 16 + c;
                        short4 o;
                        o.x = f2bf(acc[i][j][0] * sK[h * SS + tb + 0]);
                        o.y = f2bf(acc[i][j][1] * sK[h * SS + tb + 1]);
                        o.z = f2bf(acc[i][j][2] * sK[h * SS + tb + 2]);
                        o.w = f2bf(acc[i][j][3] * sK[h * SS + tb + 3]);
                        *(short4*)&Ob[(size_t)d * SS + tb] = o;
                    }
            } else {
                short* __restrict__ Ob = Vtb + (size_t)bh * HD * SS;
#pragma unroll
                for (int i = 0; i < 4; i++)
#pragma unroll
                    for (int j = 0; j < 2; j++) {
                        const int tb = s0 + wr + i * 16 + r0;
                        const int e = wc + j * 16 + c;
                        short4 o;
                        o.x = f2bf(acc[i][j][0]); o.y = f2bf(acc[i][j][1]);
                        o.z = f2bf(acc[i][j][2]); o.w = f2bf(acc[i][j][3]);
                        *(short4*)&Ob[(size_t)e * SS + tb] = o;
                    }
            }
#pragma unroll
            for (int i = 0; i < 4; i++)
#pragma unroll
                for (int j = 0; j < 2; j++) acc[i][j] = (f32x4){0.f, 0.f, 0.f, 0.f};
        }
    }
}

// ---- gate GEMM + full-K KV in one dispatch: 576 blocks x 512 thr, XCD-chunked ----
// cx = orig&7, p = orig>>3 (0..71).
// p <  64: gate role (512 blocks, K=1024) — dispatched first.
// p >= 64: kv role (64 blocks, K=1024, full): Mtb[bh] = bf16(V^T K'), backfills.
__global__ __launch_bounds__(512) void g_gatekv(
    const short* __restrict__ xb, const short* __restrict__ WgT,
    const short* __restrict__ Vtb, const short* __restrict__ Ktb,
    short* __restrict__ gateb, short* __restrict__ Mtb)
{
    __shared__ short As[2 * 8192], Bs[2 * 8192];
    f32x4 acc[4][2];
    const int orig = blockIdx.x;
    const int cx = orig & 7, p = orig >> 3;
    const int tid = threadIdx.x, lane = tid & 63, wid = tid >> 6;
    const int wr = (wid >> 2) * 64, wc = (wid & 3) * 32;
    const int r0 = (lane >> 4) * 4, c = lane & 15;

    if (p < 64) {
        // gate GEMM: gateb = ReLU(xb @ WgT^T) bf16
        const int w2 = cx * 64 + p;
        const int m0 = (w2 >> 3) * 128, n0 = (w2 & 7) * 128;
        gemm_tile_g(xb + (size_t)m0 * DD, DD, WgT + (size_t)n0 * DD, DD, DD, As, Bs, acc);
#pragma unroll
        for (int i = 0; i < 4; i++)
#pragma unroll
            for (int j = 0; j < 2; j++)
#pragma unroll
                for (int r = 0; r < 4; r++)
                    gateb[(size_t)(m0 + wr + i * 16 + r0 + r) * DD + n0 + wc + j * 16 + c] =
                        f2bf(fmaxf(acc[i][j][r], 0.f));
        return;
    }
    // KV (full K=1024): Mtb[bh][e][d] = bf16( sum_t V[t][e] * K'[t][d] )
    const int bh = cx * 8 + (p - 64);               // 0..63
    gemm_tile_g(Vtb + (size_t)bh * HD * SS, SS,
                Ktb + (size_t)bh * HD * SS, SS, SS, As, Bs, acc);
    short* __restrict__ Ob = Mtb + (size_t)bh * HD * HD;
#pragma unroll
    for (int i = 0; i < 4; i++)
#pragma unroll
        for (int j = 0; j < 2; j++)
#pragma unroll
            for (int r = 0; r < 4; r++)
                Ob[(size_t)(wr + i * 16 + r0 + r) * HD + wc + j * 16 + c] = f2bf(acc[i][j][r]);
}

// ---------- QM: single-phase K=128 (all 4 tiles resident, one barrier) ----------
//            retc[b*S+s][h*128+e] = Q' @ M + fused group-stat atomics
__global__ __launch_bounds__(512) void g_qm(
    const short* __restrict__ Qb, const short* __restrict__ Mtb,
    short* __restrict__ retc, float* __restrict__ Sp)
{
    __shared__ short As[2 * 8192], Bs[2 * 8192];
    f32x4 acc[4][2];
    const int orig = blockIdx.x;                    // 512
    const int w = (orig & 7) * 64 + (orig >> 3);
    const int bh = w >> 3, m0 = (w & 7) * 128;
    const short* __restrict__ A = Qb + ((size_t)bh * SS + m0) * HD;
    const short* __restrict__ Bp = Mtb + (size_t)bh * HD * HD;
    const int tid = threadIdx.x, lane = tid & 63, wid = tid >> 6;
    const int wr = (wid >> 2) * 64, wc = (wid & 3) * 32;
    const int fr = lane & 15, fc = lane >> 4, rsw = fr & 7;
    const int r0 = (lane >> 4) * 4, c = lane & 15;

    stage_tile(A,  HD, 0,  As,        wid, lane);
    stage_tile(A,  HD, 64, As + 8192, wid, lane);
    stage_tile(Bp, HD, 0,  Bs,        wid, lane);
    stage_tile(Bp, HD, 64, Bs + 8192, wid, lane);
#pragma unroll
    for (int i = 0; i < 4; i++)
#pragma unroll
        for (int j = 0; j < 2; j++) acc[i][j] = (f32x4){0.f, 0.f, 0.f, 0.f};
    asm volatile("s_waitcnt vmcnt(0)" ::: "memory");
    __builtin_amdgcn_s_barrier();
    __builtin_amdgcn_sched_barrier(0);
#pragma unroll
    for (int kt = 0; kt < 2; kt++) {
        const short* as = As + (kt << 13);
        const short* bs = Bs + (kt << 13);
#pragma unroll
        for (int half = 0; half < 2; half++) {
            const int slot = ((half * 4 + fc) ^ rsw) << 3;
            bf16x8 af[4], bfv[2];
#pragma unroll
            for (int i = 0; i < 4; i++) af[i] = *(const bf16x8*)&as[(wr + i * 16 + fr) * 64 + slot];
#pragma unroll
            for (int j = 0; j < 2; j++) bfv[j] = *(const bf16x8*)&bs[(wc + j * 16 + fr) * 64 + slot];
#pragma unroll
            for (int i = 0; i < 4; i++)
#pragma unroll
                for (int j = 0; j < 2; j++)
                    acc[i][j] = __builtin_amdgcn_mfma_f32_16x16x32_bf16(af[i], bfv[j], acc[i][j], 0, 0, 0);
        }
    }
    const int b_ = bh >> 3, h_ = bh & 7;
    short* __restrict__ O = retc + ((size_t)(b_ * SS + m0)) * DD + h_ * HD;
#pragma unroll
    for (int i = 0; i < 4; i++)
#pragma unroll
        for (int j = 0; j < 2; j++)
#pragma unroll
            for (int r = 0; r < 4; r++)
                O[(size_t)(wr + i * 16 + r0 + r) * DD + wc + j * 16 + c] = f2bf(acc[i][j][r]);

    // fused group stats: reduce over lane bits {0,1,2} and {4,5}: masks {1,2,4,16,32}
    float psm[2], psq[2];
#pragma unroll
    for (int j = 0; j < 2; j++) { psm[j] = 0.f; psq[j] = 0.f; }
#pragma unroll
    for (int i = 0; i < 4; i++)
#pragma unroll
        for (int j = 0; j < 2; j++)
#pragma unroll
            for (int r = 0; r < 4; r++) {
                const float v = acc[i][j][r];
                psm[j] += v; psq[j] += v * v;
            }
    const int masks[5] = {1, 2, 4, 16, 32};
#pragma unroll
    for (int mk = 0; mk < 5; mk++) {
#pragma unroll
        for (int j = 0; j < 2; j++) {
            psm[j] += __shfl_xor(psm[j], masks[mk], 64);
            psq[j] += __shfl_xor(psq[j], masks[mk], 64);
        }
    }
    if ((lane & 7) == 0 && lane < 16) {      // lanes 0 (hi=0) and 8 (hi=1)
        const int hi = lane >> 3;
#pragma unroll
        for (int j = 0; j < 2; j++) {
            const int g = b_ * 128 + h_ * 16 + (wid & 3) * 4 + j * 2 + hi;
            atomicAdd(&Sp[g * 2 + 0], psm[j]);
            atomicAdd(&Sp[g * 2 + 1], psq[j]);
        }
    }
}

// ---------------- aprep: Ab = gateb ⊙ GN(retc) -> bf16 (bf16x8 vectorized) ----------
__global__ __launch_bounds__(256) void aprep(
    const short* __restrict__ gateb, const short* __restrict__ retc,
    const float* __restrict__ Sp,
    const float* __restrict__ gng, const float* __restrict__ gnb, short* __restrict__ Ab)
{
    const size_t idx = ((size_t)blockIdx.x * 256 + threadIdx.x) * 8;
    const int m = (int)(idx >> 10), cc = (int)(idx & 1023);
    const int b_ = m >> 10, g0 = b_ * 128 + (cc >> 3);      // 8 elems span one group
    const float sm = Sp[g0 * 2 + 0], sq = Sp[g0 * 2 + 1];
    const float mu = sm * (1.0f / 8192.0f);
    float var = sq * (1.0f / 8192.0f) - mu * mu;
    if (var < 0.f) var = 0.f;
    const float rs = rsqrtf(var + GN_EPS);
    bf16x8 gv8 = *(const bf16x8*)&gateb[idx];
    bf16x8 rv8 = *(const bf16x8*)&retc[idx];
    float4 gva = *(const float4*)&gng[cc];
    float4 gvb = *(const float4*)&gng[cc + 4];
    float4 bva = *(const float4*)&gnb[cc];
    float4 bvb = *(const float4*)&gnb[cc + 4];
    const float ga[8] = {gva.x, gva.y, gva.z, gva.w, gvb.x, gvb.y, gvb.z, gvb.w};
    const float ba[8] = {bva.x, bva.y, bva.z, bva.w, bvb.x, bvb.y, bvb.z, bvb.w};
    bf16x8 o;
#pragma unroll
    for (int q = 0; q < 8; q++) {
        const float y = (bf2f(rv8[q]) - mu) * rs * ga[q] + ba[q];
        o[q] = f2bf(bf2f(gv8[q]) * y);
    }
    *(bf16x8*)&Ab[idx] = o;
}

// ---------------- final GEMM: out = Ab @ WoT^T (f32 out, XCD-chunked) ---------------
__global__ __launch_bounds__(512) void g_final(
    const short* __restrict__ Ab, const short* __restrict__ WoT, float* __restrict__ out)
{
    __shared__ short As[2 * 8192], Bs[2 * 8192];
    f32x4 acc[4][2];
    const int orig = blockIdx.x;                    // 512
    const int w = (orig & 7) * 64 + (orig >> 3);
    const int m0 = (w >> 3) * 128, n0 = (w & 7) * 128;
    gemm_tile_g(Ab + (size_t)m0 * DD, DD, WoT + (size_t)n0 * DD, DD, DD, As, Bs, acc);
    const int tid = threadIdx.x, lane = tid & 63, wid = tid >> 6;
    const int wr = (wid >> 2) * 64, wc = (wid & 3) * 32;
    const int r0 = (lane >> 4) * 4, c = lane & 15;
#pragma unroll
    for (int i = 0; i < 4; i++)
#pragma unroll
        for (int j = 0; j < 2; j++)
#pragma unroll
            for (int r = 0; r < 4; r++)
                out[(size_t)(m0 + wr + i * 16 + r0 + r) * DD + n0 + wc + j * 16 + c] = acc[i][j][r];
}

extern "C" void kernel_launch(void* const* d_in, const int* in_sizes, int n_in,
                              void* d_out, int out_size, void* d_ws, size_t ws_size,
                              hipStream_t stream)
{
    const float* x   = (const float*)d_in[0];
    const float* Wq  = (const float*)d_in[1];
    const float* Wk  = (const float*)d_in[2];
    const float* Wv  = (const float*)d_in[3];
    const float* Wg  = (const float*)d_in[4];
    const float* Wo  = (const float*)d_in[5];
    const float* gng = (const float*)d_in[6];
    const float* gnb = (const float*)d_in[7];
    float* out = (float*)d_out;

    char* ws = (char*)d_ws;
    size_t off = 0;
    auto alloc = [&](size_t bytes) -> void* {
        void* p = ws + off;
        off += (bytes + 255) & ~(size_t)255;
        return p;
    };
    const size_t NE = (size_t)BB * SS * DD;   // 8,388,608
    float*  sQ    = (float*)alloc((size_t)HH * SS * sizeof(float));
    float*  sK    = (float*)alloc((size_t)HH * SS * sizeof(float));
    short*  xb    = (short*)alloc(NE * sizeof(short));
    short*  WgT   = (short*)alloc((size_t)DD * DD * sizeof(short));
    short*  WoT   = (short*)alloc((size_t)DD * DD * sizeof(short));
    short*  Wt    = (short*)alloc((size_t)24 * HD * HD * sizeof(short));
    short*  Qb    = (short*)alloc(NE * sizeof(short));
    short*  Ktb   = (short*)alloc(NE * sizeof(short));
    short*  Vtb   = (short*)alloc(NE * sizeof(short));
    short*  retc  = (short*)alloc(NE * sizeof(short));
    short*  gateb = (short*)alloc(NE * sizeof(short));
    short*  Ab    = (short*)alloc(NE * sizeof(short));
    short*  Mtb   = (short*)alloc((size_t)64 * HD * HD * sizeof(short));
    float*  Sp    = (float*)alloc((size_t)1024 * 2 * sizeof(float));

    prep<<<dim3(6561), 256, 0, stream>>>(x, Wq, Wk, Wv, Wg, Wo, xb, WgT, WoT, Wt, sQ, sK, Sp);
    g_qkv<<<dim3(512), 512, 0, stream>>>(xb, Wt, sQ, sK, Qb, Ktb, Vtb);
    g_gatekv<<<dim3(576), 512, 0, stream>>>(xb, WgT, Vtb, Ktb, gateb, Mtb);
    g_qm<<<dim3(512), 512, 0, stream>>>(Qb, Mtb, retc, Sp);
    aprep<<<dim3(4096), 256, 0, stream>>>(gateb, retc, Sp, gng, gnb, Ab);
    g_final<<<dim3(512), 512, 0, stream>>>(Ab, WoT, out);
}

// Round 23
// 110.684 us; speedup vs baseline: 1.0239x; 1.0239x over previous
//
#include <hip/hip_runtime.h>

#define BB 8
#define SS 1024
#define DD 1024
#define HH 8
#define HD 128
#define GN_EPS 1e-3f

typedef __attribute__((ext_vector_type(8))) short bf16x8;
typedef __attribute__((ext_vector_type(4))) float f32x4;

__device__ __forceinline__ short f2bf(float f) {
    unsigned u = __float_as_uint(f);
    return (short)((u + 0x7fffu + ((u >> 16) & 1u)) >> 16);
}
__device__ __forceinline__ float bf2f(short s) {
    return __uint_as_float(((unsigned)(unsigned short)s) << 16);
}

__device__ __forceinline__ void gload16(const void* g, void* l) {
    __builtin_amdgcn_global_load_lds((const __attribute__((address_space(1))) void*)g,
                                     (__attribute__((address_space(3))) void*)l, 16, 0, 0);
}

// ---- stage one 128x64-short tile (16 KB) via global_load_lds, 8 waves ----
// LDS: linear [row][8 chunks of 8 shorts], 128 B/row. Chunk-swizzled content:
// slot q of row r holds GLOBAL chunk q ^ (r&7) (pre-swizzled global source;
// gload_lds dest stays linear). Read side applies the same XOR.
__device__ __forceinline__ void stage_tile(const short* __restrict__ G, size_t ld, int k0,
                                           short* lds, int wid, int lane) {
#pragma unroll
    for (int i = 0; i < 2; i++) {
        const int seg = wid * 2 + i;                 // 0..15 (8 rows each)
        const int row = seg * 8 + (lane >> 3);       // 0..127
        const int chunk = (lane & 7) ^ (lane >> 3);  // slot ^ (row&7)
        gload16(G + (size_t)row * ld + k0 + chunk * 8, lds + seg * 512);
    }
}

// ------------- 128x128xK MFMA core: 8 waves, BK=64, counted-vmcnt pipeline -----------
__device__ __forceinline__ void gemm_tile_g(
    const short* __restrict__ A, size_t ldA,
    const short* __restrict__ B, size_t ldB,
    int K, short* As, short* Bs, f32x4 acc[4][2])
{
    const int tid = threadIdx.x, lane = tid & 63, wid = tid >> 6;
    const int wr = (wid >> 2) * 64, wc = (wid & 3) * 32;
    const int fr = lane & 15, fc = lane >> 4;
    const int rsw = fr & 7;
#pragma unroll
    for (int i = 0; i < 4; i++)
#pragma unroll
        for (int j = 0; j < 2; j++) acc[i][j] = (f32x4){0.f, 0.f, 0.f, 0.f};

    const int nt = K >> 6;
    stage_tile(A, ldA, 0, As, wid, lane);
    stage_tile(B, ldB, 0, Bs, wid, lane);
    if (nt > 1) {
        stage_tile(A, ldA, 64, As + 8192, wid, lane);
        stage_tile(B, ldB, 64, Bs + 8192, wid, lane);
    }
    for (int t = 0; t < nt; t++) {
        if (t + 1 < nt) asm volatile("s_waitcnt vmcnt(4)" ::: "memory");
        else            asm volatile("s_waitcnt vmcnt(0)" ::: "memory");
        __builtin_amdgcn_s_barrier();
        __builtin_amdgcn_sched_barrier(0);
        const int cur = t & 1;
        const short* as = As + (cur << 13);
        const short* bs = Bs + (cur << 13);
#pragma unroll
        for (int half = 0; half < 2; half++) {
            const int slot = ((half * 4 + fc) ^ rsw) << 3;
            bf16x8 af[4], bfv[2];
#pragma unroll
            for (int i = 0; i < 4; i++) af[i] = *(const bf16x8*)&as[(wr + i * 16 + fr) * 64 + slot];
#pragma unroll
            for (int j = 0; j < 2; j++) bfv[j] = *(const bf16x8*)&bs[(wc + j * 16 + fr) * 64 + slot];
#pragma unroll
            for (int i = 0; i < 4; i++)
#pragma unroll
                for (int j = 0; j < 2; j++)
                    acc[i][j] = __builtin_amdgcn_mfma_f32_16x16x32_bf16(af[i], bfv[j], acc[i][j], 0, 0, 0);
        }
        __builtin_amdgcn_sched_barrier(0);
        asm volatile("s_waitcnt lgkmcnt(0)" ::: "memory");
        __builtin_amdgcn_s_barrier();
        if (t + 2 < nt) {
            stage_tile(A, ldA, (t + 2) << 6, As + (cur << 13), wid, lane);
            stage_tile(B, ldB, (t + 2) << 6, Bs + (cur << 13), wid, lane);
        }
    }
}

// ---------------- prep: x->bf16, W transposes, scales, zero Sp ----------------
__global__ __launch_bounds__(256) void prep(
    const float* __restrict__ x,
    const float* __restrict__ Wq, const float* __restrict__ Wk, const float* __restrict__ Wv,
    const float* __restrict__ Wg, const float* __restrict__ Wo,
    short* __restrict__ xb, short* __restrict__ WgT, short* __restrict__ WoT,
    short* __restrict__ Wt, float* __restrict__ sQ, float* __restrict__ sK,
    float* __restrict__ Sp)
{
    __shared__ float t[32][33];
    int bid = blockIdx.x;
    const int tid = threadIdx.x;
    if (bid < 4096) {                       // x -> bf16 flat
        const size_t i = ((size_t)bid * 256 + tid) * 8;
        float4 a = *(const float4*)&x[i];
        float4 b = *(const float4*)&x[i + 4];
        bf16x8 v;
        v[0] = f2bf(a.x); v[1] = f2bf(a.y); v[2] = f2bf(a.z); v[3] = f2bf(a.w);
        v[4] = f2bf(b.x); v[5] = f2bf(b.y); v[6] = f2bf(b.z); v[7] = f2bf(b.w);
        *(bf16x8*)&xb[i] = v;
        return;
    }
    bid -= 4096;
    if (bid < 2048) {                       // Wg / Wo transpose -> bf16
        const float* __restrict__ S = (bid < 1024) ? Wg : Wo;
        short* __restrict__ D = (bid < 1024) ? WgT : WoT;
        const int tb = bid & 1023;
        const int bx = (tb & 31) * 32, by = (tb >> 5) * 32;
        const int xx = tid & 31, y0 = tid >> 5;
#pragma unroll
        for (int r = 0; r < 32; r += 8) t[y0 + r][xx] = S[(size_t)(by + y0 + r) * 1024 + bx + xx];
        __syncthreads();
#pragma unroll
        for (int r = 0; r < 32; r += 8) D[(size_t)(bx + y0 + r) * 1024 + by + xx] = f2bf(t[xx][y0 + r]);
        return;
    }
    bid -= 2048;
    if (bid < 384) {                        // 24 head matrices
        const int ht = bid >> 4, tb = bid & 15;
        const int typ = ht >> 3, h = ht & 7;
        const float* __restrict__ W = (typ == 0 ? Wq : (typ == 1 ? Wk : Wv)) + (size_t)h * HD * HD;
        short* __restrict__ D = Wt + (size_t)ht * HD * HD;
        const int bx = (tb & 3) * 32, by = (tb >> 2) * 32;
        const int xx = tid & 31, y0 = tid >> 5;
#pragma unroll
        for (int r = 0; r < 32; r += 8) t[y0 + r][xx] = W[(by + y0 + r) * HD + bx + xx];
        __syncthreads();
#pragma unroll
        for (int r = 0; r < 32; r += 8) D[(bx + y0 + r) * HD + by + xx] = f2bf(t[xx][y0 + r]);
        return;
    }
    bid -= 384;
    if (bid < 32) {                         // decay scale tables
        const int h = bid >> 2;
        const int s = (bid & 3) * 256 + tid;
        const double gamma = 1.0 - exp2((double)(-5 - h));
        const double lg = log2(gamma);
        sQ[h * SS + s] = (float)exp2(lg * (double)s);
        sK[h * SS + s] = (float)exp2(-lg * (double)s);
        return;
    }
    // last block: zero Sp[2048]
    *(float4*)&Sp[tid * 8] = (float4){0.f, 0.f, 0.f, 0.f};
    *(float4*)&Sp[tid * 8 + 4] = (float4){0.f, 0.f, 0.f, 0.f};
}

// ---- gate GEMM + QKV (A-reuse) in one dispatch: 1024 blocks x 512 thr, XCD-chunked --
// cx = orig&7, p = orig>>3 (0..127).
// p <  64: gate role (512 blocks, 128x128 tile, K=1024) — dispatched first.
// p >= 64: qkv role (512 blocks): one block per (m-tile, head) computes Q,K,V.
__global__ __launch_bounds__(512) void g_qkvgate(
    const short* __restrict__ xb, const short* __restrict__ Wt, const short* __restrict__ WgT,
    const float* __restrict__ sQ, const float* __restrict__ sK,
    short* __restrict__ Qb, short* __restrict__ Ktb, short* __restrict__ Vtb,
    short* __restrict__ gateb)
{
    __shared__ short As[2 * 8192], Bs[2 * 8192];
    f32x4 acc[4][2];
    const int orig = blockIdx.x;
    const int cx = orig & 7, p = orig >> 3;
    const int tid = threadIdx.x, lane = tid & 63, wid = tid >> 6;
    const int wr = (wid >> 2) * 64, wc = (wid & 3) * 32;
    const int r0 = (lane >> 4) * 4, c = lane & 15;

    if (p < 64) {
        // gate GEMM: gateb = ReLU(xb @ WgT^T) bf16
        const int w2 = cx * 64 + p;
        const int m0 = (w2 >> 3) * 128, n0 = (w2 & 7) * 128;
        gemm_tile_g(xb + (size_t)m0 * DD, DD, WgT + (size_t)n0 * DD, DD, DD, As, Bs, acc);
#pragma unroll
        for (int i = 0; i < 4; i++)
#pragma unroll
            for (int j = 0; j < 2; j++)
#pragma unroll
                for (int r = 0; r < 4; r++)
                    gateb[(size_t)(m0 + wr + i * 16 + r0 + r) * DD + n0 + wc + j * 16 + c] =
                        f2bf(fmaxf(acc[i][j][r], 0.f));
        return;
    }
    // ---------------- QKV, A-reuse ----------------
    const int w = cx * 64 + (p - 64);               // 0..511
    const int mt = w >> 3, h = w & 7;
    const int m0 = mt * 128;
    const int b = m0 >> 10, s0 = m0 & (SS - 1);
    const int bh = (b << 3) + h;
    const short* __restrict__ A = xb + (size_t)m0 * DD + h * HD;

    const int fr = lane & 15, fc = lane >> 4;
    const int rsw = fr & 7;

    // prologue: both A K-tiles (resident) + first B tile
    stage_tile(A, DD, 0,  As,        wid, lane);
    stage_tile(A, DD, 64, As + 8192, wid, lane);
    stage_tile(Wt + (size_t)h * HD * HD, HD, 0, Bs, wid, lane);
    __syncthreads();

#pragma unroll
    for (int i = 0; i < 4; i++)
#pragma unroll
        for (int j = 0; j < 2; j++) acc[i][j] = (f32x4){0.f, 0.f, 0.f, 0.f};

    int sb = 0;
    for (int st = 0; st < 6; st++) {                // st = typ*2 + kt
        if (st + 1 < 6) {
            const int typn = (st + 1) >> 1, ktn = (st + 1) & 1;
            stage_tile(Wt + (size_t)(typn * 8 + h) * HD * HD, HD, ktn * 64,
                       Bs + ((sb ^ 1) << 13), wid, lane);
        }
        const int kt = st & 1;
        const short* as = As + (kt << 13);
        const short* bs = Bs + (sb << 13);
#pragma unroll
        for (int half = 0; half < 2; half++) {
            const int slot = ((half * 4 + fc) ^ rsw) << 3;
            bf16x8 af[4], bfv[2];
#pragma unroll
            for (int i = 0; i < 4; i++) af[i] = *(const bf16x8*)&as[(wr + i * 16 + fr) * 64 + slot];
#pragma unroll
            for (int j = 0; j < 2; j++) bfv[j] = *(const bf16x8*)&bs[(wc + j * 16 + fr) * 64 + slot];
#pragma unroll
            for (int i = 0; i < 4; i++)
#pragma unroll
                for (int j = 0; j < 2; j++)
                    acc[i][j] = __builtin_amdgcn_mfma_f32_16x16x32_bf16(af[i], bfv[j], acc[i][j], 0, 0, 0);
        }
        __syncthreads();                             // drains B stage + protects buffers
        sb ^= 1;
        if (kt == 1) {                               // finished a type: epilogue + reset
            const int typ = st >> 1;
            if (typ == 0) {
#pragma unroll
                for (int i = 0; i < 4; i++)
#pragma unroll
                    for (int j = 0; j < 2; j++)
#pragma unroll
                        for (int r = 0; r < 4; r++) {
                            const int s = s0 + wr + i * 16 + r0 + r;
                            Qb[((size_t)bh * SS + s) * HD + wc + j * 16 + c] =
                                f2bf(acc[i][j][r] * sQ[h * SS + s]);
                        }
            } else if (typ == 1) {
                short* __restrict__ Ob = Ktb + (size_t)bh * HD * SS;
#pragma unroll
                for (int i = 0; i < 4; i++)
#pragma unroll
                    for (int j = 0; j < 2; j++) {
                        const int tb = s0 + wr + i * 16 + r0;
                        const int d = wc + j * 16 + c;
                        short4 o;
                        o.x = f2bf(acc[i][j][0] * sK[h * SS + tb + 0]);
                        o.y = f2bf(acc[i][j][1] * sK[h * SS + tb + 1]);
                        o.z = f2bf(acc[i][j][2] * sK[h * SS + tb + 2]);
                        o.w = f2bf(acc[i][j][3] * sK[h * SS + tb + 3]);
                        *(short4*)&Ob[(size_t)d * SS + tb] = o;
                    }
            } else {
                short* __restrict__ Ob = Vtb + (size_t)bh * HD * SS;
#pragma unroll
                for (int i = 0; i < 4; i++)
#pragma unroll
                    for (int j = 0; j < 2; j++) {
                        const int tb = s0 + wr + i * 16 + r0;
                        const int e = wc + j * 16 + c;
                        short4 o;
                        o.x = f2bf(acc[i][j][0]); o.y = f2bf(acc[i][j][1]);
                        o.z = f2bf(acc[i][j][2]); o.w = f2bf(acc[i][j][3]);
                        *(short4*)&Ob[(size_t)e * SS + tb] = o;
                    }
            }
#pragma unroll
            for (int i = 0; i < 4; i++)
#pragma unroll
                for (int j = 0; j < 2; j++) acc[i][j] = (f32x4){0.f, 0.f, 0.f, 0.f};
        }
    }
}

// ---------------- KV: split-2 over t (K=512/block), 128 blocks, XCD-chunked ---------
__global__ __launch_bounds__(512) void g_kv(
    const short* __restrict__ Vtb, const short* __restrict__ Ktb, float* __restrict__ Mp)
{
    __shared__ short As[2 * 8192], Bs[2 * 8192];
    f32x4 acc[4][2];
    const int orig = blockIdx.x;                    // 128
    const int w = (orig & 7) * 16 + (orig >> 3);    // 0..127
    const int chunk = w & 1, bh = w >> 1;
    gemm_tile_g(Vtb + (size_t)bh * HD * SS + chunk * 512, SS,
                Ktb + (size_t)bh * HD * SS + chunk * 512, SS, 512, As, Bs, acc);
    const int tid = threadIdx.x, lane = tid & 63, wid = tid >> 6;
    const int wr = (wid >> 2) * 64, wc = (wid & 3) * 32;
    const int r0 = (lane >> 4) * 4, c = lane & 15;
    float* __restrict__ Ob = Mp + (size_t)w * HD * HD;
#pragma unroll
    for (int i = 0; i < 4; i++)
#pragma unroll
        for (int j = 0; j < 2; j++)
#pragma unroll
            for (int r = 0; r < 4; r++)
                Ob[(size_t)(wr + i * 16 + r0 + r) * HD + wc + j * 16 + c] = acc[i][j][r];
}

// ---------------- reduce 2 chunks + cvt: Mtb[bh][e][d] bf16 ----------------
__global__ __launch_bounds__(256) void g_mredcvt(const float* __restrict__ Mp, short* __restrict__ Mtb) {
    const size_t i = ((size_t)blockIdx.x * 256 + threadIdx.x) * 8;
    const size_t bh = i >> 14, ij = i & 16383;
    const float* p = Mp + (bh * 2) * 16384 + ij;
    float s[8];
#pragma unroll
    for (int q = 0; q < 8; q++) s[q] = 0.f;
#pragma unroll
    for (int cth = 0; cth < 2; cth++) {
        float4 a = *(const float4*)&p[cth * 16384];
        float4 b = *(const float4*)&p[cth * 16384 + 4];
        s[0] += a.x; s[1] += a.y; s[2] += a.z; s[3] += a.w;
        s[4] += b.x; s[5] += b.y; s[6] += b.z; s[7] += b.w;
    }
    bf16x8 v;
#pragma unroll
    for (int q = 0; q < 8; q++) v[q] = f2bf(s[q]);
    *(bf16x8*)&Mtb[i] = v;
}

// ---------- QM: single-phase K=128 (all 4 tiles resident, one barrier) ----------
//            retc[b*S+s][h*128+e] = Q' @ M + fused group-stat atomics
__global__ __launch_bounds__(512) void g_qm(
    const short* __restrict__ Qb, const short* __restrict__ Mtb,
    short* __restrict__ retc, float* __restrict__ Sp)
{
    __shared__ short As[2 * 8192], Bs[2 * 8192];
    f32x4 acc[4][2];
    const int orig = blockIdx.x;                    // 512
    const int w = (orig & 7) * 64 + (orig >> 3);
    const int bh = w >> 3, m0 = (w & 7) * 128;
    const short* __restrict__ A = Qb + ((size_t)bh * SS + m0) * HD;
    const short* __restrict__ Bp = Mtb + (size_t)bh * HD * HD;
    const int tid = threadIdx.x, lane = tid & 63, wid = tid >> 6;
    const int wr = (wid >> 2) * 64, wc = (wid & 3) * 32;
    const int fr = lane & 15, fc = lane >> 4, rsw = fr & 7;
    const int r0 = (lane >> 4) * 4, c = lane & 15;

    stage_tile(A,  HD, 0,  As,        wid, lane);
    stage_tile(A,  HD, 64, As + 8192, wid, lane);
    stage_tile(Bp, HD, 0,  Bs,        wid, lane);
    stage_tile(Bp, HD, 64, Bs + 8192, wid, lane);
#pragma unroll
    for (int i = 0; i < 4; i++)
#pragma unroll
        for (int j = 0; j < 2; j++) acc[i][j] = (f32x4){0.f, 0.f, 0.f, 0.f};
    asm volatile("s_waitcnt vmcnt(0)" ::: "memory");
    __builtin_amdgcn_s_barrier();
    __builtin_amdgcn_sched_barrier(0);
#pragma unroll
    for (int kt = 0; kt < 2; kt++) {
        const short* as = As + (kt << 13);
        const short* bs = Bs + (kt << 13);
#pragma unroll
        for (int half = 0; half < 2; half++) {
            const int slot = ((half * 4 + fc) ^ rsw) << 3;
            bf16x8 af[4], bfv[2];
#pragma unroll
            for (int i = 0; i < 4; i++) af[i] = *(const bf16x8*)&as[(wr + i * 16 + fr) * 64 + slot];
#pragma unroll
            for (int j = 0; j < 2; j++) bfv[j] = *(const bf16x8*)&bs[(wc + j * 16 + fr) * 64 + slot];
#pragma unroll
            for (int i = 0; i < 4; i++)
#pragma unroll
                for (int j = 0; j < 2; j++)
                    acc[i][j] = __builtin_amdgcn_mfma_f32_16x16x32_bf16(af[i], bfv[j], acc[i][j], 0, 0, 0);
        }
    }
    const int b_ = bh >> 3, h_ = bh & 7;
    short* __restrict__ O = retc + ((size_t)(b_ * SS + m0)) * DD + h_ * HD;
#pragma unroll
    for (int i = 0; i < 4; i++)
#pragma unroll
        for (int j = 0; j < 2; j++)
#pragma unroll
            for (int r = 0; r < 4; r++)
                O[(size_t)(wr + i * 16 + r0 + r) * DD + wc + j * 16 + c] = f2bf(acc[i][j][r]);

    // fused group stats: reduce over lane bits {0,1,2} and {4,5}: masks {1,2,4,16,32}
    float psm[2], psq[2];
#pragma unroll
    for (int j = 0; j < 2; j++) { psm[j] = 0.f; psq[j] = 0.f; }
#pragma unroll
    for (int i = 0; i < 4; i++)
#pragma unroll
        for (int j = 0; j < 2; j++)
#pragma unroll
            for (int r = 0; r < 4; r++) {
                const float v = acc[i][j][r];
                psm[j] += v; psq[j] += v * v;
            }
    const int masks[5] = {1, 2, 4, 16, 32};
#pragma unroll
    for (int mk = 0; mk < 5; mk++) {
#pragma unroll
        for (int j = 0; j < 2; j++) {
            psm[j] += __shfl_xor(psm[j], masks[mk], 64);
            psq[j] += __shfl_xor(psq[j], masks[mk], 64);
        }
    }
    if ((lane & 7) == 0 && lane < 16) {      // lanes 0 (hi=0) and 8 (hi=1)
        const int hi = lane >> 3;
#pragma unroll
        for (int j = 0; j < 2; j++) {
            const int g = b_ * 128 + h_ * 16 + (wid & 3) * 4 + j * 2 + hi;
            atomicAdd(&Sp[g * 2 + 0], psm[j]);
            atomicAdd(&Sp[g * 2 + 1], psq[j]);
        }
    }
}

// ---------------- aprep: Ab = gateb ⊙ GN(retc) -> bf16 (bf16x8 vectorized) ----------
__global__ __launch_bounds__(256) void aprep(
    const short* __restrict__ gateb, const short* __restrict__ retc,
    const float* __restrict__ Sp,
    const float* __restrict__ gng, const float* __restrict__ gnb, short* __restrict__ Ab)
{
    const size_t idx = ((size_t)blockIdx.x * 256 + threadIdx.x) * 8;
    const int m = (int)(idx >> 10), cc = (int)(idx & 1023);
    const int b_ = m >> 10, g0 = b_ * 128 + (cc >> 3);      // 8 elems span one group
    const float sm = Sp[g0 * 2 + 0], sq = Sp[g0 * 2 + 1];
    const float mu = sm * (1.0f / 8192.0f);
    float var = sq * (1.0f / 8192.0f) - mu * mu;
    if (var < 0.f) var = 0.f;
    const float rs = rsqrtf(var + GN_EPS);
    bf16x8 gv8 = *(const bf16x8*)&gateb[idx];
    bf16x8 rv8 = *(const bf16x8*)&retc[idx];
    float4 gva = *(const float4*)&gng[cc];
    float4 gvb = *(const float4*)&gng[cc + 4];
    float4 bva = *(const float4*)&gnb[cc];
    float4 bvb = *(const float4*)&gnb[cc + 4];
    const float ga[8] = {gva.x, gva.y, gva.z, gva.w, gvb.x, gvb.y, gvb.z, gvb.w};
    const float ba[8] = {bva.x, bva.y, bva.z, bva.w, bvb.x, bvb.y, bvb.z, bvb.w};
    bf16x8 o;
#pragma unroll
    for (int q = 0; q < 8; q++) {
        const float y = (bf2f(rv8[q]) - mu) * rs * ga[q] + ba[q];
        o[q] = f2bf(bf2f(gv8[q]) * y);
    }
    *(bf16x8*)&Ab[idx] = o;
}

// ---------------- final GEMM: out = Ab @ WoT^T (f32 out, XCD-chunked) ---------------
__global__ __launch_bounds__(512) void g_final(
    const short* __restrict__ Ab, const short* __restrict__ WoT, float* __restrict__ out)
{
    __shared__ short As[2 * 8192], Bs[2 * 8192];
    f32x4 acc[4][2];
    const int orig = blockIdx.x;                    // 512
    const int w = (orig & 7) * 64 + (orig >> 3);
    const int m0 = (w >> 3) * 128, n0 = (w & 7) * 128;
    gemm_tile_g(Ab + (size_t)m0 * DD, DD, WoT + (size_t)n0 * DD, DD, DD, As, Bs, acc);
    const int tid = threadIdx.x, lane = tid & 63, wid = tid >> 6;
    const int wr = (wid >> 2) * 64, wc = (wid & 3) * 32;
    const int r0 = (lane >> 4) * 4, c = lane & 15;
#pragma unroll
    for (int i = 0; i < 4; i++)
#pragma unroll
        for (int j = 0; j < 2; j++)
#pragma unroll
            for (int r = 0; r < 4; r++)
                out[(size_t)(m0 + wr + i * 16 + r0 + r) * DD + n0 + wc + j * 16 + c] = acc[i][j][r];
}

extern "C" void kernel_launch(void* const* d_in, const int* in_sizes, int n_in,
                              void* d_out, int out_size, void* d_ws, size_t ws_size,
                              hipStream_t stream)
{
    const float* x   = (const float*)d_in[0];
    const float* Wq  = (const float*)d_in[1];
    const float* Wk  = (const float*)d_in[2];
    const float* Wv  = (const float*)d_in[3];
    const float* Wg  = (const float*)d_in[4];
    const float* Wo  = (const float*)d_in[5];
    const float* gng = (const float*)d_in[6];
    const float* gnb = (const float*)d_in[7];
    float* out = (float*)d_out;

    char* ws = (char*)d_ws;
    size_t off = 0;
    auto alloc = [&](size_t bytes) -> void* {
        void* p = ws + off;
        off += (bytes + 255) & ~(size_t)255;
        return p;
    };
    const size_t NE = (size_t)BB * SS * DD;   // 8,388,608
    float*  sQ    = (float*)alloc((size_t)HH * SS * sizeof(float));
    float*  sK    = (float*)alloc((size_t)HH * SS * sizeof(float));
    short*  xb    = (short*)alloc(NE * sizeof(short));
    short*  WgT   = (short*)alloc((size_t)DD * DD * sizeof(short));
    short*  WoT   = (short*)alloc((size_t)DD * DD * sizeof(short));
    short*  Wt    = (short*)alloc((size_t)24 * HD * HD * sizeof(short));
    short*  Qb    = (short*)alloc(NE * sizeof(short));
    short*  Ktb   = (short*)alloc(NE * sizeof(short));
    short*  Vtb   = (short*)alloc(NE * sizeof(short));
    short*  retc  = (short*)alloc(NE * sizeof(short));
    short*  gateb = (short*)alloc(NE * sizeof(short));
    short*  Ab    = (short*)alloc(NE * sizeof(short));
    float*  Mp    = (float*)alloc((size_t)128 * HD * HD * sizeof(float));
    short*  Mtb   = (short*)alloc((size_t)64 * HD * HD * sizeof(short));
    float*  Sp    = (float*)alloc((size_t)1024 * 2 * sizeof(float));

    prep<<<dim3(6561), 256, 0, stream>>>(x, Wq, Wk, Wv, Wg, Wo, xb, WgT, WoT, Wt, sQ, sK, Sp);
    g_qkvgate<<<dim3(1024), 512, 0, stream>>>(xb, Wt, WgT, sQ, sK, Qb, Ktb, Vtb, gateb);
    g_kv<<<dim3(128), 512, 0, stream>>>(Vtb, Ktb, Mp);
    g_mredcvt<<<dim3(512), 256, 0, stream>>>(Mp, Mtb);
    g_qm<<<dim3(512), 512, 0, stream>>>(Qb, Mtb, retc, Sp);
    aprep<<<dim3(4096), 256, 0, stream>>>(gateb, retc, Sp, gng, gnb, Ab);
    g_final<<<dim3(512), 512, 0, stream>>>(Ab, WoT, out);
}